// Round 5
// baseline (333.718 us; speedup 1.0000x reference)
//
#include <hip/hip_runtime.h>
#include <hip/hip_bf16.h>

// Shapes (fixed by the problem): B=4, S=2048, D=1024, H=16, Dh=64.
// Pipeline:
//   1) fused prep: cast resid fp32->bf16; transpose W_Q/K/V -> [3072 n][1024 k];
//      W_out -> W2t [1024 d][1024 hc]   (one kernel, block-id dispatch)
//   2) gemm_deep<1>: QKV projection, 128x256 tile, counted-vmcnt (3 groups in
//      flight, vmcnt(6)), 96 KiB LDS, XOR swizzle key (row>>1)&3. 768 blocks.
//   3) flash attention: BARRIER-FREE. K/V fragments stream L2->VGPR directly
//      (no LDS staging; per-XCD working set = 8 heads x 512 KB = 4 MB = one
//      L2). Only per-wave P buffer in LDS. 5 blocks/CU. Fixed-max softmax,
//      ls via ones-MFMA.
//   4) gemm_deep<0>: out = Z @ W2t + b_out (fp32), same deep structure.

typedef short s16x8 __attribute__((ext_vector_type(8)));
typedef short s16x4 __attribute__((ext_vector_type(4)));
typedef float f32x4 __attribute__((ext_vector_type(4)));

#define MFMA_BF16(A, B, C) __builtin_amdgcn_mfma_f32_16x16x32_bf16((A), (B), (C), 0, 0, 0)

#if __has_builtin(__builtin_amdgcn_exp2f)
#define EXP2(x) __builtin_amdgcn_exp2f(x)
#else
#define EXP2(x) exp2f(x)
#endif
#if __has_builtin(__builtin_amdgcn_rcpf)
#define RCP(x) __builtin_amdgcn_rcpf(x)
#else
#define RCP(x) (1.0f / (x))
#endif

__device__ __forceinline__ short f2bf(float f) {
    __bf16 h = (__bf16)f;              // RNE convert
    return __builtin_bit_cast(short, h);
}

// async global->LDS, 16 B per lane. LDS dest = wave-uniform base + 16*lane.
__device__ __forceinline__ void gld16(const unsigned short* g, unsigned short* l) {
    __builtin_amdgcn_global_load_lds(
        (const __attribute__((address_space(1))) unsigned int*)g,
        (__attribute__((address_space(3))) unsigned int*)l, 16, 0, 0);
}

// ---------------- 1) fused prep: cast + 4 weight transposes ----------------
// blocks [0,8192): cast; [8192,8448): WQ; +256: WK; +256: WV; +256: Wout.
__global__ __launch_bounds__(256) void prep_fused(
    const float* __restrict__ resid, const float* __restrict__ WQ,
    const float* __restrict__ WK, const float* __restrict__ WV,
    const float* __restrict__ Wout,
    unsigned short* __restrict__ residb, unsigned short* __restrict__ Wqkvt,
    unsigned short* __restrict__ W2t)
{
    const int bid = blockIdx.x;
    if (bid < 8192) {                     // cast 8192*1024 floats, float4 per thread
        const int i = bid * 256 + threadIdx.x;
        const float4 v = ((const float4*)resid)[i];
        s16x4 o;
        o[0] = f2bf(v.x); o[1] = f2bf(v.y); o[2] = f2bf(v.z); o[3] = f2bf(v.w);
        *(s16x4*)(residb + (size_t)i * 4) = o;
        return;
    }
    __shared__ unsigned short tile[64][66];
    const int id2 = bid - 8192;
    const int which = id2 >> 8;           // 0..3
    const int sub = id2 & 255;
    const int tx = threadIdx.x & 63, ty = threadIdx.x >> 6;
    if (which < 3) {                      // W[k][n] 1024x1024 -> Wt[n][k] bf16
        const float* W = which == 0 ? WQ : (which == 1 ? WK : WV);
        unsigned short* Wt = Wqkvt + (size_t)which * 1024 * 1024;
        const int n0 = (sub & 15) * 64, k0 = (sub >> 4) * 64;
        #pragma unroll
        for (int i = ty; i < 64; i += 4)
            tile[i][tx] = (unsigned short)f2bf(W[(size_t)(k0 + i) * 1024 + n0 + tx]);
        __syncthreads();
        #pragma unroll
        for (int i = ty; i < 64; i += 4)
            Wt[(size_t)(n0 + i) * 1024 + k0 + tx] = tile[tx][i];
    } else {                              // W_out[c][h][d] -> W2t[d][h*64+c]
        const int d0 = (sub & 15) * 64, h = sub >> 4;
        #pragma unroll
        for (int c = ty; c < 64; c += 4)
            tile[c][tx] = (unsigned short)f2bf(Wout[(size_t)(c * 16 + h) * 1024 + d0 + tx]);
        __syncthreads();
        #pragma unroll
        for (int i = ty; i < 64; i += 4)
            W2t[(size_t)(d0 + i) * 1024 + h * 64 + tx] = tile[tx][i];
    }
}

// ---------------- 2)/4) deep GEMM: 128x256 tile, counted-vmcnt -------------
// C[M][N] = A[M][1024] * Bt[N][1024]^T.
// MODE 1: N=3072, outputs split Q/K/Vt (bf16).  MODE 0: N=1024, fp32 C + bias.
// 8 waves (2M x 4N), per-wave C = 64x64 = acc[4][4] frags.
// LDS (dynamic, 96 KiB): 2 buffers x {A_klo[128][32], A_khi, B_klo[256][32],
// B_khi} (64-B row pitch). XOR swizzle key (row>>1)&3 on 16B slots: applied
// on the DMA SOURCE address (LDS dest linear) and on ds_read offsets ->
// b128 reads at the hardware-minimum 8 bank-cycles (conflict-free).
// Load groups (3x gld16 = 24 KB): Glo(t)={A_klo,B_klo0,B_klo1},
// Ghi(t)={A_khi,B_khi0,B_khi1} -> buf[t&1].
// Issue order: prologue Glo(0),Ghi(0),Glo(1); in-loop Ghi(t+1) @ kk0(t),
// Glo(t+2) @ kk1(t)  [targets proven idle]. Prefetch distance = 3 phases.
// Ledger (steady): 9 outstanding at each W-point, oldest 3 = group being
// consumed -> vmcnt(6). Tail: W1(15)=vmcnt(3), W2(15)=vmcnt(0).
template <int MODE>
__global__ __launch_bounds__(512, 2) void gemm_deep(
    const unsigned short* __restrict__ A,
    const unsigned short* __restrict__ Bt,
    unsigned short* __restrict__ Qb, unsigned short* __restrict__ Kb,
    unsigned short* __restrict__ Vt,
    float* __restrict__ Cf, const float* __restrict__ bias)
{
    extern __shared__ __align__(16) unsigned short S[];
    constexpr int LDK = 1024, NT = 16;      // K=1024, BK=64
    constexpr int NBX = (MODE == 1) ? 12 : 4;   // N tiles of 256
    constexpr int XCH = (MODE == 1) ? 96 : 32;  // blocks per XCD (grid%8==0)
    const int tid = threadIdx.x, lane = tid & 63, w = tid >> 6;
    const int wm = w >> 2, wn = w & 3;      // 2 x 4 waves
    const int quad = lane >> 4, fl = lane & 15;

    const int wg  = blockIdx.x;
    const int swz = (wg & 7) * XCH + (wg >> 3);
    const int bx  = swz % NBX, by = swz / NBX;
    const int m0  = by * 128, n0 = bx * 256;

    // --- staging sources. One gld16 = 512 thr x 16 B = 8 KB (one A-half /
    // half a B-half). thread tid -> arena row tid/4, phys slot tid&3;
    // source k-chunk = (tid&3) ^ ((tid>>3)&3)  [key (row>>1)&3].
    const int srow = tid >> 2;                                  // 0..127
    const int sk   = ((tid & 3) ^ ((tid >> 3) & 3)) * 8;        // shorts
    const unsigned short* pa  = A  + (size_t)(m0 + srow) * LDK + sk;
    const unsigned short* pb0 = Bt + (size_t)(n0 + srow) * LDK + sk;
    const unsigned short* pb1 = Bt + (size_t)(n0 + 128 + srow) * LDK + sk;
    const int dst = tid * 8;                 // LDS shorts within arena

    // --- compute-side LDS read offsets (shorts). key = (fl>>1)&3 for all frags.
    const int sx   = (quad ^ ((fl >> 1) & 3)) * 8;
    const int arow = (wm * 64 + fl) * 32 + sx;           // A_klo@0, A_khi@4096
    const int brow = 8192 + (wn * 64 + fl) * 32 + sx;    // B_klo@8192, B_khi@16384

    f32x4 acc[4][4];
    #pragma unroll
    for (int m = 0; m < 4; ++m)
        #pragma unroll
        for (int n = 0; n < 4; ++n) acc[m][n] = (f32x4){0.f, 0.f, 0.f, 0.f};

    // --- prologue: Glo(0), Ghi(0) -> buf0; Glo(1) -> buf1. (9 loads) ---
    gld16(pa,       S + dst);                // A_klo(0)
    gld16(pb0,      S + 8192 + dst);         // B_klo(0) rows 0-127
    gld16(pb1,      S + 12288 + dst);        // B_klo(0) rows 128-255
    gld16(pa + 32,  S + 4096 + dst);         // A_khi(0)
    gld16(pb0 + 32, S + 16384 + dst);        // B_khi(0) rows 0-127
    gld16(pb1 + 32, S + 20480 + dst);        // B_khi(0) rows 128-255
    gld16(pa + 64,  S + 24576 + dst);        // A_klo(1)
    gld16(pb0 + 64, S + 24576 + 8192 + dst); // B_klo(1) rows 0-127
    gld16(pb1 + 64, S + 24576 + 12288 + dst);// B_klo(1) rows 128-255

    for (int t = 0; t < NT; ++t) {
        unsigned short* Sc = S + (t & 1) * 24576;
        unsigned short* Sn = S + ((t & 1) ^ 1) * 24576;

        // W1: Glo(t) landed (oldest 3 of 9 in steady state).
        if (t < NT - 1) asm volatile("s_waitcnt vmcnt(6)" ::: "memory");
        else            asm volatile("s_waitcnt vmcnt(3)" ::: "memory");
        __builtin_amdgcn_s_barrier();

        s16x8 af[4], bfr[4];
        // ---- phase kk=0: read klo(t), issue Ghi(t+1) -> Sn.khi ----
        #pragma unroll
        for (int mi = 0; mi < 4; ++mi) af[mi]  = *(const s16x8*)(Sc + arow + mi * 512);
        #pragma unroll
        for (int ni = 0; ni < 4; ++ni) bfr[ni] = *(const s16x8*)(Sc + brow + ni * 512);
        if (t < NT - 1) {
            const int ka = (t + 1) * 64 + 32;
            gld16(pa + ka,  Sn + 4096 + dst);            // A_khi(t+1)
            gld16(pb0 + ka, Sn + 16384 + dst);           // B_khi(t+1)
            gld16(pb1 + ka, Sn + 20480 + dst);
        }
        asm volatile("" ::: "memory");
        __builtin_amdgcn_s_barrier();
        __builtin_amdgcn_s_setprio(1);
        #pragma unroll
        for (int mi = 0; mi < 4; ++mi)
            #pragma unroll
            for (int ni = 0; ni < 4; ++ni)
                acc[mi][ni] = MFMA_BF16(af[mi], bfr[ni], acc[mi][ni]);
        __builtin_amdgcn_s_setprio(0);

        // W2: Ghi(t) landed.
        if (t < NT - 1) asm volatile("s_waitcnt vmcnt(6)" ::: "memory");
        else            asm volatile("s_waitcnt vmcnt(0)" ::: "memory");
        __builtin_amdgcn_s_barrier();
        // ---- phase kk=1: read khi(t), issue Glo(t+2) -> Sc.klo ----
        // (Sc.klo's reads all completed before the W2 barrier above.)
        #pragma unroll
        for (int mi = 0; mi < 4; ++mi) af[mi]  = *(const s16x8*)(Sc + 4096 + arow + mi * 512);
        #pragma unroll
        for (int ni = 0; ni < 4; ++ni) bfr[ni] = *(const s16x8*)(Sc + 8192 + brow + ni * 512);
        if (t < NT - 2) {
            const int ka = (t + 2) * 64;
            gld16(pa + ka,  Sc + dst);                   // A_klo(t+2)
            gld16(pb0 + ka, Sc + 8192 + dst);            // B_klo(t+2)
            gld16(pb1 + ka, Sc + 12288 + dst);
        }
        asm volatile("" ::: "memory");
        __builtin_amdgcn_s_barrier();
        __builtin_amdgcn_s_setprio(1);
        #pragma unroll
        for (int mi = 0; mi < 4; ++mi)
            #pragma unroll
            for (int ni = 0; ni < 4; ++ni)
                acc[mi][ni] = MFMA_BF16(af[mi], bfr[ni], acc[mi][ni]);
        __builtin_amdgcn_s_setprio(0);
        // loop top of t+1 = W1 wait + barrier (keeps ds reads of buf safe).
    }

    // ---- epilogue. C/D frag layout: row = quad*4 + r, col = fl. ----
    if (MODE == 0) {
        #pragma unroll
        for (int ni = 0; ni < 4; ++ni) {
            const int col = n0 + wn * 64 + ni * 16 + fl;
            const float bv = bias[col];
            #pragma unroll
            for (int mi = 0; mi < 4; ++mi) {
                const int row = m0 + wm * 64 + mi * 16 + quad * 4;
                #pragma unroll
                for (int r = 0; r < 4; ++r)
                    Cf[(size_t)(row + r) * 1024 + col] = acc[mi][ni][r] + bv;
            }
        }
    } else {
        // Block cols span exactly one of Q/K/V (n0 multiple of 256).
        const int which = n0 >> 10;
        if (which < 2) {
            unsigned short* O = which == 0 ? Qb : Kb;
            const int cbase = (n0 & 1023) + wn * 64;
            #pragma unroll
            for (int mi = 0; mi < 4; ++mi) {
                const int row = m0 + wm * 64 + mi * 16 + quad * 4;
                #pragma unroll
                for (int ni = 0; ni < 4; ++ni) {
                    const int col = cbase + ni * 16 + fl;
                    #pragma unroll
                    for (int r = 0; r < 4; ++r)
                        O[(size_t)(row + r) * 1024 + col] = (unsigned short)f2bf(acc[mi][ni][r]);
                }
            }
        } else {
            // V transposed: Vt[((b*16+h)*64+c)][s]; r-values s-consecutive -> 8B store
            const int hh = ((n0 - 2048) >> 6) + wn;             // wave-uniform head
            #pragma unroll
            for (int mi = 0; mi < 4; ++mi) {
                const int token = m0 + wm * 64 + mi * 16 + quad * 4;
                const int bb = token >> 11, ss = token & 2047;
                #pragma unroll
                for (int ni = 0; ni < 4; ++ni) {
                    const int cl = ni * 16 + fl;
                    s16x4 pv;
                    pv[0] = f2bf(acc[mi][ni][0]); pv[1] = f2bf(acc[mi][ni][1]);
                    pv[2] = f2bf(acc[mi][ni][2]); pv[3] = f2bf(acc[mi][ni][3]);
                    *(s16x4*)(Vt + (size_t)((bb * 16 + hh) * 64 + cl) * 2048 + ss) = pv;
                }
            }
        }
    }
}

// ---------------- 3) attention tile body (DIAG templated) ----------------
// Direct-from-L2 K/V fragment loads (no LDS staging, no barriers).
// Kt = Kbase + fl*1024 + quad*8 advanced by 128*1024/tile; frag f at +f*16384.
// Vl = Vbase + fl*2048 + quad*8 advanced by 128/tile; frag (mf,c4) at
// +mf*32768 + c4*32. ls accumulation on the matrix pipe via ones-MFMA
// (rowsum of the bf16 P actually used in PV -> denominator matches numerator).
template <bool DIAG>
__device__ __forceinline__ void attn_tile(
    int s0, int wl, int wq0, int fl, int quad,
    const unsigned short* __restrict__ Kt, const unsigned short* __restrict__ Vl,
    unsigned short* __restrict__ PbW,
    const s16x8 (&qfr)[2][2], f32x4 (&zt)[2][4], f32x4 (&lsa)[2])
{
    const float SC = 0.18033688011112042f;   // (1/sqrt(64)) * log2(e)
    const float M  = 32.0f;                  // fixed softmax shift
    const s16x8 ones = {16256, 16256, 16256, 16256, 16256, 16256, 16256, 16256};
    #pragma unroll
    for (int c4 = 0; c4 < 4; ++c4) {
        if (DIAG && c4 > wl) break;          // wave-uniform causal skip
        #pragma unroll
        for (int e = 0; e < 2; ++e) {
            const int f = 2 * c4 + e;
            const s16x8 kf0 = *(const s16x8*)(Kt + f * 16384);
            const s16x8 kf1 = *(const s16x8*)(Kt + f * 16384 + 32);
            #pragma unroll
            for (int g = 0; g < 2; ++g) {
                unsigned short* pw = PbW + (g * 16 + fl) * 36 + e * 16 + quad * 4;
                if (DIAG && f > 2 * wl + g) { // fully masked frag: zero-fill
                    *(s16x4*)pw = (s16x4){0, 0, 0, 0};
                } else {
                    f32x4 z = (f32x4){0.f, 0.f, 0.f, 0.f};
                    z = MFMA_BF16(kf0, qfr[g][0], z);
                    z = MFMA_BF16(kf1, qfr[g][1], z);
                    float p[4];
                    #pragma unroll
                    for (int r = 0; r < 4; ++r) {
                        float arg = fmaf(z[r], SC, -M);
                        if (DIAG && f == 2 * wl + g) {   // diagonal frag only
                            const int s = s0 + f * 16 + quad * 4 + r;
                            const int qi = wq0 + g * 16 + fl;
                            if (s > qi) arg = -100.f;    // exp2 -> ~0
                        }
                        p[r] = EXP2(arg);
                    }
                    s16x4 pk;
                    pk[0] = f2bf(p[0]); pk[1] = f2bf(p[1]);
                    pk[2] = f2bf(p[2]); pk[3] = f2bf(p[3]);
                    *(s16x4*)pw = pk;
                }
            }
        }
        // PV + denominator for this 32-s chunk (MFMA cluster: setprio)
        const s16x8 pf0 = *(const s16x8*)(PbW + fl * 36 + quad * 8);
        const s16x8 pf1 = *(const s16x8*)(PbW + (16 + fl) * 36 + quad * 8);
        __builtin_amdgcn_s_setprio(1);
        lsa[0] = MFMA_BF16(ones, pf0, lsa[0]);
        lsa[1] = MFMA_BF16(ones, pf1, lsa[1]);
        #pragma unroll
        for (int mf = 0; mf < 4; ++mf) {
            const s16x8 vf = *(const s16x8*)(Vl + mf * 32768 + c4 * 32);
            zt[0][mf] = MFMA_BF16(vf, pf0, zt[0][mf]);
            zt[1][mf] = MFMA_BF16(vf, pf1, zt[1][mf]);
        }
        __builtin_amdgcn_s_setprio(0);
    }
}

// ---------------- 3) causal flash attention, barrier-free ----------------
// 256-thread blocks (4 waves), 128 q/block, grid 1024 heavy-first:
// qb = 15 - (lid>>6)  (LPT scheduling). bh = lid&63 -> XCD = lid%8 = bh%8
// keeps each XCD's 8 heads' K+V (4 MiB) hot in its L2. No __syncthreads:
// waves are fully independent (per-wave P buffer only); K/V stream L2->VGPR.
__global__ __launch_bounds__(256, 5) void attn_causal(
    const unsigned short* __restrict__ Qb,
    const unsigned short* __restrict__ Kb,
    const unsigned short* __restrict__ Vt,
    unsigned short* __restrict__ Zb)
{
    __shared__ __align__(16) unsigned short Pb[4][32 * 36]; // per wave [32 q][32 s + pad]
    const int tid = threadIdx.x, lane = tid & 63, w = tid >> 6;
    const int quad = lane >> 4, fl = lane & 15;
    const int lid = blockIdx.x;
    const int qb = 15 - (lid >> 6);             // heavy-first
    const int bh = lid & 63, b = bh >> 4, h = bh & 15;
    const int wq0 = qb * 128 + w * 32;          // wave's first q row
    const int wl = w;                           // wave's slot in the 128-q tile

    unsigned short* PbW = Pb[w];

    // Q fragments: [g][half]
    s16x8 qfr[2][2];
    #pragma unroll
    for (int g = 0; g < 2; ++g) {
        const unsigned short* Qrow = Qb + (size_t)(b * 2048 + wq0 + g * 16 + fl) * 1024 + h * 64;
        qfr[g][0] = *(const s16x8*)(Qrow + quad * 8);
        qfr[g][1] = *(const s16x8*)(Qrow + 32 + quad * 8);
    }

    // Per-lane running K/V pointers (advanced per 128-s tile).
    const unsigned short* Kt = Kb + (size_t)b * 2048 * 1024 + h * 64
                                  + (size_t)fl * 1024 + quad * 8;
    const unsigned short* Vl = Vt + (size_t)bh * 64 * 2048
                                  + (size_t)fl * 2048 + quad * 8;

    f32x4 zt[2][4];                              // [g][mf] accumulators
    #pragma unroll
    for (int g = 0; g < 2; ++g)
        #pragma unroll
        for (int mf = 0; mf < 4; ++mf) zt[g][mf] = (f32x4){0.f, 0.f, 0.f, 0.f};
    f32x4 lsa[2] = {(f32x4){0.f, 0.f, 0.f, 0.f}, (f32x4){0.f, 0.f, 0.f, 0.f}};

    for (int kt = 0; kt < qb; ++kt) {
        attn_tile<false>(kt << 7, wl, wq0, fl, quad, Kt, Vl, PbW, qfr, zt, lsa);
        Kt += 128 * 1024;
        Vl += 128;
    }
    attn_tile<true>(qb << 7, wl, wq0, fl, quad, Kt, Vl, PbW, qfr, zt, lsa);

    // ---- normalize + store Z. lsa rows all equal -> element 0 is the rowsum.
    #pragma unroll
    for (int g = 0; g < 2; ++g) {
        const float inv = RCP(lsa[g][0]);
        unsigned short* Zrow = Zb + (size_t)(b * 2048 + wq0 + g * 16 + fl) * 1024 + h * 64;
        #pragma unroll
        for (int mf = 0; mf < 4; ++mf) {
            s16x4 o;
            o[0] = f2bf(zt[g][mf][0] * inv); o[1] = f2bf(zt[g][mf][1] * inv);
            o[2] = f2bf(zt[g][mf][2] * inv); o[3] = f2bf(zt[g][mf][3] * inv);
            *(s16x4*)(Zrow + mf * 16 + quad * 4) = o;
        }
    }
}

// ---------------- launch ----------------
extern "C" void kernel_launch(void* const* d_in, const int* in_sizes, int n_in,
                              void* d_out, int out_size, void* d_ws, size_t ws_size,
                              hipStream_t stream) {
    const float* resid = (const float*)d_in[0];
    const float* WQ    = (const float*)d_in[1];
    const float* WK    = (const float*)d_in[2];
    const float* WV    = (const float*)d_in[3];
    const float* Wout  = (const float*)d_in[4];
    const float* bout  = (const float*)d_in[5];
    float* out = (float*)d_out;

    char* p = (char*)d_ws;
    auto alloc = [&](size_t bytes) { void* r = (void*)p; p += (bytes + 255) & ~(size_t)255; return r; };
    unsigned short* residb = (unsigned short*)alloc(8192ull * 1024 * 2);
    unsigned short* Wqkvt  = (unsigned short*)alloc(3072ull * 1024 * 2);
    unsigned short* W2t    = (unsigned short*)alloc(1024ull * 1024 * 2);
    unsigned short* Qbuf   = (unsigned short*)alloc(8192ull * 1024 * 2);
    unsigned short* Kbuf   = (unsigned short*)alloc(8192ull * 1024 * 2);
    unsigned short* Vtb    = (unsigned short*)alloc(64ull * 64 * 2048 * 2);
    unsigned short* Zbuf   = (unsigned short*)alloc(8192ull * 1024 * 2);

    static bool s_attr = false;
    if (!s_attr) {                           // host-side attr set; graph-capture-safe
        hipFuncSetAttribute(reinterpret_cast<const void*>(gemm_deep<1>),
                            hipFuncAttributeMaxDynamicSharedMemorySize, 98304);
        hipFuncSetAttribute(reinterpret_cast<const void*>(gemm_deep<0>),
                            hipFuncAttributeMaxDynamicSharedMemorySize, 98304);
        s_attr = true;
    }

    prep_fused<<<9216, 256, 0, stream>>>(resid, WQ, WK, WV, Wout, residb, Wqkvt, W2t);
    gemm_deep<1><<<768, 512, 98304, stream>>>(residb, Wqkvt, Qbuf, Kbuf, Vtb,
                                              nullptr, nullptr);
    attn_causal<<<1024, 256, 0, stream>>>(Qbuf, Kbuf, Vtb, Zbuf);
    gemm_deep<0><<<256, 512, 98304, stream>>>(Zbuf, W2t, nullptr, nullptr, nullptr,
                                              out, bout);
}

// Round 6
// 311.843 us; speedup vs baseline: 1.0701x; 1.0701x over previous
//
#include <hip/hip_runtime.h>
#include <hip/hip_bf16.h>

// Shapes (fixed by the problem): B=4, S=2048, D=1024, H=16, Dh=64.
// Pipeline:
//   1) fused prep: cast resid fp32->bf16; transpose W_Q/K/V -> [3072 n][1024 k];
//      W_out -> W2t [1024 d][1024 hc]   (one kernel, block-id dispatch)
//   2) gemm_deep<1>: QKV projection, 128x256 tile, counted-vmcnt (3 groups in
//      flight, vmcnt(6)), 96 KiB LDS, XOR swizzle key (row>>1)&3. 768 blocks.
//   3) flash attention: K/V LDS-staged via T14 async-STAGE split (issue
//      global->reg loads one full tile early; ds_write at tile start ->
//      latency hidden under compute, no full-drain stall). 128-q blocks
//      (4 waves), LPT grid 1024, 3 blocks/CU. Fixed-max softmax, ls via
//      ones-MFMA.
//   4) gemm_deep<0>: out = Z @ W2t + b_out (fp32), same deep structure.

typedef short s16x8 __attribute__((ext_vector_type(8)));
typedef short s16x4 __attribute__((ext_vector_type(4)));
typedef float f32x4 __attribute__((ext_vector_type(4)));

#define MFMA_BF16(A, B, C) __builtin_amdgcn_mfma_f32_16x16x32_bf16((A), (B), (C), 0, 0, 0)

#if __has_builtin(__builtin_amdgcn_exp2f)
#define EXP2(x) __builtin_amdgcn_exp2f(x)
#else
#define EXP2(x) exp2f(x)
#endif
#if __has_builtin(__builtin_amdgcn_rcpf)
#define RCP(x) __builtin_amdgcn_rcpf(x)
#else
#define RCP(x) (1.0f / (x))
#endif

__device__ __forceinline__ short f2bf(float f) {
    __bf16 h = (__bf16)f;              // RNE convert
    return __builtin_bit_cast(short, h);
}

// async global->LDS, 16 B per lane. LDS dest = wave-uniform base + 16*lane.
__device__ __forceinline__ void gld16(const unsigned short* g, unsigned short* l) {
    __builtin_amdgcn_global_load_lds(
        (const __attribute__((address_space(1))) unsigned int*)g,
        (__attribute__((address_space(3))) unsigned int*)l, 16, 0, 0);
}

// ---------------- 1) fused prep: cast + 4 weight transposes ----------------
// blocks [0,8192): cast; [8192,8448): WQ; +256: WK; +256: WV; +256: Wout.
__global__ __launch_bounds__(256) void prep_fused(
    const float* __restrict__ resid, const float* __restrict__ WQ,
    const float* __restrict__ WK, const float* __restrict__ WV,
    const float* __restrict__ Wout,
    unsigned short* __restrict__ residb, unsigned short* __restrict__ Wqkvt,
    unsigned short* __restrict__ W2t)
{
    const int bid = blockIdx.x;
    if (bid < 8192) {                     // cast 8192*1024 floats, float4 per thread
        const int i = bid * 256 + threadIdx.x;
        const float4 v = ((const float4*)resid)[i];
        s16x4 o;
        o[0] = f2bf(v.x); o[1] = f2bf(v.y); o[2] = f2bf(v.z); o[3] = f2bf(v.w);
        *(s16x4*)(residb + (size_t)i * 4) = o;
        return;
    }
    __shared__ unsigned short tile[64][66];
    const int id2 = bid - 8192;
    const int which = id2 >> 8;           // 0..3
    const int sub = id2 & 255;
    const int tx = threadIdx.x & 63, ty = threadIdx.x >> 6;
    if (which < 3) {                      // W[k][n] 1024x1024 -> Wt[n][k] bf16
        const float* W = which == 0 ? WQ : (which == 1 ? WK : WV);
        unsigned short* Wt = Wqkvt + (size_t)which * 1024 * 1024;
        const int n0 = (sub & 15) * 64, k0 = (sub >> 4) * 64;
        #pragma unroll
        for (int i = ty; i < 64; i += 4)
            tile[i][tx] = (unsigned short)f2bf(W[(size_t)(k0 + i) * 1024 + n0 + tx]);
        __syncthreads();
        #pragma unroll
        for (int i = ty; i < 64; i += 4)
            Wt[(size_t)(n0 + i) * 1024 + k0 + tx] = tile[tx][i];
    } else {                              // W_out[c][h][d] -> W2t[d][h*64+c]
        const int d0 = (sub & 15) * 64, h = sub >> 4;
        #pragma unroll
        for (int c = ty; c < 64; c += 4)
            tile[c][tx] = (unsigned short)f2bf(Wout[(size_t)(c * 16 + h) * 1024 + d0 + tx]);
        __syncthreads();
        #pragma unroll
        for (int i = ty; i < 64; i += 4)
            W2t[(size_t)(d0 + i) * 1024 + h * 64 + tx] = tile[tx][i];
    }
}

// ---------------- 2)/4) deep GEMM: 128x256 tile, counted-vmcnt -------------
// C[M][N] = A[M][1024] * Bt[N][1024]^T.
// MODE 1: N=3072, outputs split Q/K/Vt (bf16).  MODE 0: N=1024, fp32 C + bias.
// 8 waves (2M x 4N), per-wave C = 64x64 = acc[4][4] frags.
// LDS (dynamic, 96 KiB): 2 buffers x {A_klo[128][32], A_khi, B_klo[256][32],
// B_khi} (64-B row pitch). XOR swizzle key (row>>1)&3 on 16B slots: applied
// on the DMA SOURCE address (LDS dest linear) and on ds_read offsets ->
// b128 reads at the hardware-minimum 8 bank-cycles (conflict-free).
// Load groups (3x gld16 = 24 KB): Glo(t)={A_klo,B_klo0,B_klo1},
// Ghi(t)={A_khi,B_khi0,B_khi1} -> buf[t&1].
// Issue order: prologue Glo(0),Ghi(0),Glo(1); in-loop Ghi(t+1) @ kk0(t),
// Glo(t+2) @ kk1(t)  [targets proven idle]. Prefetch distance = 3 phases.
// Ledger (steady): 9 outstanding at each W-point, oldest 3 = group being
// consumed -> vmcnt(6). Tail: W1(15)=vmcnt(3), W2(15)=vmcnt(0).
template <int MODE>
__global__ __launch_bounds__(512, 2) void gemm_deep(
    const unsigned short* __restrict__ A,
    const unsigned short* __restrict__ Bt,
    unsigned short* __restrict__ Qb, unsigned short* __restrict__ Kb,
    unsigned short* __restrict__ Vt,
    float* __restrict__ Cf, const float* __restrict__ bias)
{
    extern __shared__ __align__(16) unsigned short S[];
    constexpr int LDK = 1024, NT = 16;      // K=1024, BK=64
    constexpr int NBX = (MODE == 1) ? 12 : 4;   // N tiles of 256
    constexpr int XCH = (MODE == 1) ? 96 : 32;  // blocks per XCD (grid%8==0)
    const int tid = threadIdx.x, lane = tid & 63, w = tid >> 6;
    const int wm = w >> 2, wn = w & 3;      // 2 x 4 waves
    const int quad = lane >> 4, fl = lane & 15;

    const int wg  = blockIdx.x;
    const int swz = (wg & 7) * XCH + (wg >> 3);
    const int bx  = swz % NBX, by = swz / NBX;
    const int m0  = by * 128, n0 = bx * 256;

    // --- staging sources. One gld16 = 512 thr x 16 B = 8 KB (one A-half /
    // half a B-half). thread tid -> arena row tid/4, phys slot tid&3;
    // source k-chunk = (tid&3) ^ ((tid>>3)&3)  [key (row>>1)&3].
    const int srow = tid >> 2;                                  // 0..127
    const int sk   = ((tid & 3) ^ ((tid >> 3) & 3)) * 8;        // shorts
    const unsigned short* pa  = A  + (size_t)(m0 + srow) * LDK + sk;
    const unsigned short* pb0 = Bt + (size_t)(n0 + srow) * LDK + sk;
    const unsigned short* pb1 = Bt + (size_t)(n0 + 128 + srow) * LDK + sk;
    const int dst = tid * 8;                 // LDS shorts within arena

    // --- compute-side LDS read offsets (shorts). key = (fl>>1)&3 for all frags.
    const int sx   = (quad ^ ((fl >> 1) & 3)) * 8;
    const int arow = (wm * 64 + fl) * 32 + sx;           // A_klo@0, A_khi@4096
    const int brow = 8192 + (wn * 64 + fl) * 32 + sx;    // B_klo@8192, B_khi@16384

    f32x4 acc[4][4];
    #pragma unroll
    for (int m = 0; m < 4; ++m)
        #pragma unroll
        for (int n = 0; n < 4; ++n) acc[m][n] = (f32x4){0.f, 0.f, 0.f, 0.f};

    // --- prologue: Glo(0), Ghi(0) -> buf0; Glo(1) -> buf1. (9 loads) ---
    gld16(pa,       S + dst);                // A_klo(0)
    gld16(pb0,      S + 8192 + dst);         // B_klo(0) rows 0-127
    gld16(pb1,      S + 12288 + dst);        // B_klo(0) rows 128-255
    gld16(pa + 32,  S + 4096 + dst);         // A_khi(0)
    gld16(pb0 + 32, S + 16384 + dst);        // B_khi(0) rows 0-127
    gld16(pb1 + 32, S + 20480 + dst);        // B_khi(0) rows 128-255
    gld16(pa + 64,  S + 24576 + dst);        // A_klo(1)
    gld16(pb0 + 64, S + 24576 + 8192 + dst); // B_klo(1) rows 0-127
    gld16(pb1 + 64, S + 24576 + 12288 + dst);// B_klo(1) rows 128-255

    for (int t = 0; t < NT; ++t) {
        unsigned short* Sc = S + (t & 1) * 24576;
        unsigned short* Sn = S + ((t & 1) ^ 1) * 24576;

        // W1: Glo(t) landed (oldest 3 of 9 in steady state).
        if (t < NT - 1) asm volatile("s_waitcnt vmcnt(6)" ::: "memory");
        else            asm volatile("s_waitcnt vmcnt(3)" ::: "memory");
        __builtin_amdgcn_s_barrier();

        s16x8 af[4], bfr[4];
        // ---- phase kk=0: read klo(t), issue Ghi(t+1) -> Sn.khi ----
        #pragma unroll
        for (int mi = 0; mi < 4; ++mi) af[mi]  = *(const s16x8*)(Sc + arow + mi * 512);
        #pragma unroll
        for (int ni = 0; ni < 4; ++ni) bfr[ni] = *(const s16x8*)(Sc + brow + ni * 512);
        if (t < NT - 1) {
            const int ka = (t + 1) * 64 + 32;
            gld16(pa + ka,  Sn + 4096 + dst);            // A_khi(t+1)
            gld16(pb0 + ka, Sn + 16384 + dst);           // B_khi(t+1)
            gld16(pb1 + ka, Sn + 20480 + dst);
        }
        asm volatile("" ::: "memory");
        __builtin_amdgcn_s_barrier();
        __builtin_amdgcn_s_setprio(1);
        #pragma unroll
        for (int mi = 0; mi < 4; ++mi)
            #pragma unroll
            for (int ni = 0; ni < 4; ++ni)
                acc[mi][ni] = MFMA_BF16(af[mi], bfr[ni], acc[mi][ni]);
        __builtin_amdgcn_s_setprio(0);

        // W2: Ghi(t) landed.
        if (t < NT - 1) asm volatile("s_waitcnt vmcnt(6)" ::: "memory");
        else            asm volatile("s_waitcnt vmcnt(0)" ::: "memory");
        __builtin_amdgcn_s_barrier();
        // ---- phase kk=1: read khi(t), issue Glo(t+2) -> Sc.klo ----
        // (Sc.klo's reads all completed before the W2 barrier above.)
        #pragma unroll
        for (int mi = 0; mi < 4; ++mi) af[mi]  = *(const s16x8*)(Sc + 4096 + arow + mi * 512);
        #pragma unroll
        for (int ni = 0; ni < 4; ++ni) bfr[ni] = *(const s16x8*)(Sc + 8192 + brow + ni * 512);
        if (t < NT - 2) {
            const int ka = (t + 2) * 64;
            gld16(pa + ka,  Sc + dst);                   // A_klo(t+2)
            gld16(pb0 + ka, Sc + 8192 + dst);            // B_klo(t+2)
            gld16(pb1 + ka, Sc + 12288 + dst);
        }
        asm volatile("" ::: "memory");
        __builtin_amdgcn_s_barrier();
        __builtin_amdgcn_s_setprio(1);
        #pragma unroll
        for (int mi = 0; mi < 4; ++mi)
            #pragma unroll
            for (int ni = 0; ni < 4; ++ni)
                acc[mi][ni] = MFMA_BF16(af[mi], bfr[ni], acc[mi][ni]);
        __builtin_amdgcn_s_setprio(0);
        // loop top of t+1 = W1 wait + barrier (keeps ds reads of buf safe).
    }

    // ---- epilogue. C/D frag layout: row = quad*4 + r, col = fl. ----
    if (MODE == 0) {
        #pragma unroll
        for (int ni = 0; ni < 4; ++ni) {
            const int col = n0 + wn * 64 + ni * 16 + fl;
            const float bv = bias[col];
            #pragma unroll
            for (int mi = 0; mi < 4; ++mi) {
                const int row = m0 + wm * 64 + mi * 16 + quad * 4;
                #pragma unroll
                for (int r = 0; r < 4; ++r)
                    Cf[(size_t)(row + r) * 1024 + col] = acc[mi][ni][r] + bv;
            }
        }
    } else {
        // Block cols span exactly one of Q/K/V (n0 multiple of 256).
        const int which = n0 >> 10;
        if (which < 2) {
            unsigned short* O = which == 0 ? Qb : Kb;
            const int cbase = (n0 & 1023) + wn * 64;
            #pragma unroll
            for (int mi = 0; mi < 4; ++mi) {
                const int row = m0 + wm * 64 + mi * 16 + quad * 4;
                #pragma unroll
                for (int ni = 0; ni < 4; ++ni) {
                    const int col = cbase + ni * 16 + fl;
                    #pragma unroll
                    for (int r = 0; r < 4; ++r)
                        O[(size_t)(row + r) * 1024 + col] = (unsigned short)f2bf(acc[mi][ni][r]);
                }
            }
        } else {
            // V transposed: Vt[((b*16+h)*64+c)][s]; r-values s-consecutive -> 8B store
            const int hh = ((n0 - 2048) >> 6) + wn;             // wave-uniform head
            #pragma unroll
            for (int mi = 0; mi < 4; ++mi) {
                const int token = m0 + wm * 64 + mi * 16 + quad * 4;
                const int bb = token >> 11, ss = token & 2047;
                #pragma unroll
                for (int ni = 0; ni < 4; ++ni) {
                    const int cl = ni * 16 + fl;
                    s16x4 pv;
                    pv[0] = f2bf(acc[mi][ni][0]); pv[1] = f2bf(acc[mi][ni][1]);
                    pv[2] = f2bf(acc[mi][ni][2]); pv[3] = f2bf(acc[mi][ni][3]);
                    *(s16x4*)(Vt + (size_t)((bb * 16 + hh) * 64 + cl) * 2048 + ss) = pv;
                }
            }
        }
    }
}

// ---------------- 3) attention tile body (DIAG templated) ----------------
// ls accumulation on the matrix pipe: lsa[g] += ones^T . P (rowsum of the
// bf16 P actually used in PV -> denominator matches numerator). All D rows
// equal -> final ls = lsa[g][0], no cross-lane reduce.
template <bool DIAG>
__device__ __forceinline__ void attn_tile(
    int s0, int wl, int wq0, int fl, int quad,
    const unsigned short* __restrict__ KV, const unsigned short* __restrict__ Vs,
    unsigned short* __restrict__ PbW,
    const s16x8 (&qfr)[2][2], f32x4 (&zt)[2][4], f32x4 (&lsa)[2])
{
    const float SC = 0.18033688011112042f;   // (1/sqrt(64)) * log2(e)
    const float M  = 32.0f;                  // fixed softmax shift
    const s16x8 ones = {16256, 16256, 16256, 16256, 16256, 16256, 16256, 16256};
    #pragma unroll
    for (int c4 = 0; c4 < 4; ++c4) {
        if (DIAG && c4 > wl) break;          // wave-uniform causal skip
        #pragma unroll
        for (int e = 0; e < 2; ++e) {
            const int f = 2 * c4 + e;
            const unsigned short* Krow = KV + (f * 16 + fl) * 72;
            const s16x8 kf0 = *(const s16x8*)(Krow + quad * 8);
            const s16x8 kf1 = *(const s16x8*)(Krow + 32 + quad * 8);
            #pragma unroll
            for (int g = 0; g < 2; ++g) {
                unsigned short* pw = PbW + (g * 16 + fl) * 36 + e * 16 + quad * 4;
                if (DIAG && f > 2 * wl + g) { // fully masked frag: zero-fill
                    *(s16x4*)pw = (s16x4){0, 0, 0, 0};
                } else {
                    f32x4 z = (f32x4){0.f, 0.f, 0.f, 0.f};
                    z = MFMA_BF16(kf0, qfr[g][0], z);
                    z = MFMA_BF16(kf1, qfr[g][1], z);
                    float p[4];
                    #pragma unroll
                    for (int r = 0; r < 4; ++r) {
                        float arg = fmaf(z[r], SC, -M);
                        if (DIAG && f == 2 * wl + g) {   // diagonal frag only
                            const int s = s0 + f * 16 + quad * 4 + r;
                            const int qi = wq0 + g * 16 + fl;
                            if (s > qi) arg = -100.f;    // exp2 -> ~0
                        }
                        p[r] = EXP2(arg);
                    }
                    s16x4 pk;
                    pk[0] = f2bf(p[0]); pk[1] = f2bf(p[1]);
                    pk[2] = f2bf(p[2]); pk[3] = f2bf(p[3]);
                    *(s16x4*)pw = pk;
                }
            }
        }
        // PV + denominator for this 32-s chunk (MFMA cluster: setprio)
        const s16x8 pf0 = *(const s16x8*)(PbW + fl * 36 + quad * 8);
        const s16x8 pf1 = *(const s16x8*)(PbW + (16 + fl) * 36 + quad * 8);
        __builtin_amdgcn_s_setprio(1);
        lsa[0] = MFMA_BF16(ones, pf0, lsa[0]);
        lsa[1] = MFMA_BF16(ones, pf1, lsa[1]);
        #pragma unroll
        for (int mf = 0; mf < 4; ++mf) {
            const s16x8 vf = *(const s16x8*)(Vs + (mf * 16 + fl) * 136 + c4 * 32 + quad * 8);
            zt[0][mf] = MFMA_BF16(vf, pf0, zt[0][mf]);
            zt[1][mf] = MFMA_BF16(vf, pf1, zt[1][mf]);
        }
        __builtin_amdgcn_s_setprio(0);
    }
}

// ---------------- 3) causal flash attention, T14 async-staged ----------------
// 256-thread blocks (4 waves), 128 q/block, grid 1024 heavy-first:
// qb = 15 - (lid>>6)  (LPT scheduling, 3 blocks/CU dynamic balance).
// bh = lid&63 -> XCD = lid%8 = bh%8 keeps each XCD's 8 heads' K+V hot in L2.
// T14 staging: global->reg loads for tile t+1 issue right after tile t's
// ds_write (latency hidden under tile t's full compute); tile boundary is
// barrier -> ds_write regs -> issue next loads -> barrier (lgkm only, no
// vmcnt drain on the critical path).
__global__ __launch_bounds__(256, 3) void attn_causal(
    const unsigned short* __restrict__ Qb,
    const unsigned short* __restrict__ Kb,
    const unsigned short* __restrict__ Vt,
    unsigned short* __restrict__ Zb)
{
    __shared__ __align__(16) unsigned short KV[17920];      // K: 128x72 sh, V: 64x136 sh
    __shared__ __align__(16) unsigned short Pb[4][32 * 36]; // per wave [32 q][32 s + pad]
    const int tid = threadIdx.x, lane = tid & 63, w = tid >> 6;
    const int quad = lane >> 4, fl = lane & 15;
    const int lid = blockIdx.x;
    const int qb = 15 - (lid >> 6);             // heavy-first
    const int bh = lid & 63, b = bh >> 4, h = bh & 15;
    const int wq0 = qb * 128 + w * 32;          // wave's first q row
    const int wl = w;                           // wave's slot in the 128-q tile

    const unsigned short* Kbase = Kb + (size_t)b * 2048 * 1024 + h * 64;
    const unsigned short* Vbase = Vt + (size_t)bh * 64 * 2048;
    unsigned short* PbW = Pb[w];
    const unsigned short* Vs = KV + 9216;

    // Q fragments: [g][half]
    s16x8 qfr[2][2];
    #pragma unroll
    for (int g = 0; g < 2; ++g) {
        const unsigned short* Qrow = Qb + (size_t)(b * 2048 + wq0 + g * 16 + fl) * 1024 + h * 64;
        qfr[g][0] = *(const s16x8*)(Qrow + quad * 8);
        qfr[g][1] = *(const s16x8*)(Qrow + 32 + quad * 8);
    }

    // Staging map: 35 chunks over 4 waves (waves 0-2 get 9, wave 3 gets 8).
    const unsigned short* gsp[9];
    int sadv[9];
    unsigned ldsb[9];
    #pragma unroll
    for (int i = 0; i < 9; ++i) {
        const int W = w + 4 * i;
        if (W < 35) {
            const int c = W * 64 + lane;
            if (c < 1152) {
                const int r = c / 9, cl0 = c % 9;
                const int cl = (cl0 == 8) ? 0 : cl0;
                gsp[i] = Kbase + r * 1024 + cl * 8;  sadv[i] = 128 * 1024;
            } else {
                const int cc = c - 1152;
                const int r = cc / 17, cl0 = cc % 17;
                const int cl = (cl0 == 16) ? 0 : cl0;
                gsp[i] = Vbase + r * 2048 + cl * 8;  sadv[i] = 128;
            }
            ldsb[i] = (unsigned)c * 8u;
        }
    }

    f32x4 zt[2][4];                              // [g][mf] accumulators
    #pragma unroll
    for (int g = 0; g < 2; ++g)
        #pragma unroll
        for (int mf = 0; mf < 4; ++mf) zt[g][mf] = (f32x4){0.f, 0.f, 0.f, 0.f};
    f32x4 lsa[2] = {(f32x4){0.f, 0.f, 0.f, 0.f}, (f32x4){0.f, 0.f, 0.f, 0.f}};
    const int ntiles = qb + 1;

    // T14 prologue: issue tile-0 loads into registers.
    s16x8 rg[9];
    #pragma unroll
    for (int i = 0; i < 9; ++i)
        if (w + 4 * i < 35) {
            rg[i] = *(const s16x8*)gsp[i];
            gsp[i] += sadv[i];
        }

    for (int kt = 0; kt < ntiles; ++kt) {
        __syncthreads();                          // previous tile's LDS reads done
        // write staged regs (compiler inserts vmcnt waits per-reg as needed)
        #pragma unroll
        for (int i = 0; i < 9; ++i)
            if (w + 4 * i < 35)
                *(s16x8*)(KV + ldsb[i]) = rg[i];
        // issue next tile's loads; latency hides under this tile's compute
        if (kt + 1 < ntiles) {
            #pragma unroll
            for (int i = 0; i < 9; ++i)
                if (w + 4 * i < 35) {
                    rg[i] = *(const s16x8*)gsp[i];
                    gsp[i] += sadv[i];
                }
        }
        __syncthreads();                          // ds_writes visible to all waves

        if (kt < qb) {
            attn_tile<false>(kt << 7, wl, wq0, fl, quad, KV, Vs, PbW, qfr, zt, lsa);
        } else {
            attn_tile<true>(kt << 7, wl, wq0, fl, quad, KV, Vs, PbW, qfr, zt, lsa);
        }
    }
    // ---- normalize + store Z. lsa rows all equal -> element 0 is the rowsum.
    #pragma unroll
    for (int g = 0; g < 2; ++g) {
        const float inv = RCP(lsa[g][0]);
        unsigned short* Zrow = Zb + (size_t)(b * 2048 + wq0 + g * 16 + fl) * 1024 + h * 64;
        #pragma unroll
        for (int mf = 0; mf < 4; ++mf) {
            s16x4 o;
            o[0] = f2bf(zt[g][mf][0] * inv); o[1] = f2bf(zt[g][mf][1] * inv);
            o[2] = f2bf(zt[g][mf][2] * inv); o[3] = f2bf(zt[g][mf][3] * inv);
            *(s16x4*)(Zrow + mf * 16 + quad * 4) = o;
        }
    }
}

// ---------------- launch ----------------
extern "C" void kernel_launch(void* const* d_in, const int* in_sizes, int n_in,
                              void* d_out, int out_size, void* d_ws, size_t ws_size,
                              hipStream_t stream) {
    const float* resid = (const float*)d_in[0];
    const float* WQ    = (const float*)d_in[1];
    const float* WK    = (const float*)d_in[2];
    const float* WV    = (const float*)d_in[3];
    const float* Wout  = (const float*)d_in[4];
    const float* bout  = (const float*)d_in[5];
    float* out = (float*)d_out;

    char* p = (char*)d_ws;
    auto alloc = [&](size_t bytes) { void* r = (void*)p; p += (bytes + 255) & ~(size_t)255; return r; };
    unsigned short* residb = (unsigned short*)alloc(8192ull * 1024 * 2);
    unsigned short* Wqkvt  = (unsigned short*)alloc(3072ull * 1024 * 2);
    unsigned short* W2t    = (unsigned short*)alloc(1024ull * 1024 * 2);
    unsigned short* Qbuf   = (unsigned short*)alloc(8192ull * 1024 * 2);
    unsigned short* Kbuf   = (unsigned short*)alloc(8192ull * 1024 * 2);
    unsigned short* Vtb    = (unsigned short*)alloc(64ull * 64 * 2048 * 2);
    unsigned short* Zbuf   = (unsigned short*)alloc(8192ull * 1024 * 2);

    static bool s_attr = false;
    if (!s_attr) {                           // host-side attr set; graph-capture-safe
        hipFuncSetAttribute(reinterpret_cast<const void*>(gemm_deep<1>),
                            hipFuncAttributeMaxDynamicSharedMemorySize, 98304);
        hipFuncSetAttribute(reinterpret_cast<const void*>(gemm_deep<0>),
                            hipFuncAttributeMaxDynamicSharedMemorySize, 98304);
        s_attr = true;
    }

    prep_fused<<<9216, 256, 0, stream>>>(resid, WQ, WK, WV, Wout, residb, Wqkvt, W2t);
    gemm_deep<1><<<768, 512, 98304, stream>>>(residb, Wqkvt, Qbuf, Kbuf, Vtb,
                                              nullptr, nullptr);
    attn_causal<<<1024, 256, 0, stream>>>(Qbuf, Kbuf, Vtb, Zbuf);
    gemm_deep<0><<<256, 512, 98304, stream>>>(Zbuf, W2t, nullptr, nullptr, nullptr,
                                              out, bout);
}

// Round 7
// 248.034 us; speedup vs baseline: 1.3455x; 1.2573x over previous
//
#include <hip/hip_runtime.h>
#include <hip/hip_bf16.h>

// Shapes (fixed by the problem): B=4, S=2048, D=1024, H=16, Dh=64.
// Pipeline:
//   1) fused prep: cast resid fp32->bf16; transpose W_Q/K/V -> [3072 n][1024 k];
//      W_out -> W2t [1024 d][1024 hc]   (one kernel, block-id dispatch)
//   2) gemm_deep<1>: QKV projection, 128x256 tile, counted-vmcnt (3 groups in
//      flight, vmcnt(6)), 96 KiB LDS, XOR swizzle key (row>>1)&3. 768 blocks.
//   3) flash attention: K/V double-buffered gld16 staging (prefetch tile t+1
//      into buf^1 right after tile-t barrier; the barrier's vmcnt(0) drain
//      waits on loads issued one full tile earlier -> free). 128-q blocks
//      (4 waves), LPT grid 1024, 2 blocks/CU. Fixed-max softmax, ls via
//      ones-MFMA.
//   4) gemm_deep<0>: out = Z @ W2t + b_out (fp32), same deep structure.

typedef short s16x8 __attribute__((ext_vector_type(8)));
typedef short s16x4 __attribute__((ext_vector_type(4)));
typedef float f32x4 __attribute__((ext_vector_type(4)));

#define MFMA_BF16(A, B, C) __builtin_amdgcn_mfma_f32_16x16x32_bf16((A), (B), (C), 0, 0, 0)

#if __has_builtin(__builtin_amdgcn_exp2f)
#define EXP2(x) __builtin_amdgcn_exp2f(x)
#else
#define EXP2(x) exp2f(x)
#endif
#if __has_builtin(__builtin_amdgcn_rcpf)
#define RCP(x) __builtin_amdgcn_rcpf(x)
#else
#define RCP(x) (1.0f / (x))
#endif

__device__ __forceinline__ short f2bf(float f) {
    __bf16 h = (__bf16)f;              // RNE convert
    return __builtin_bit_cast(short, h);
}

// async global->LDS, 16 B per lane. LDS dest = wave-uniform base + 16*lane.
__device__ __forceinline__ void gld16(const unsigned short* g, unsigned short* l) {
    __builtin_amdgcn_global_load_lds(
        (const __attribute__((address_space(1))) unsigned int*)g,
        (__attribute__((address_space(3))) unsigned int*)l, 16, 0, 0);
}

// ---------------- 1) fused prep: cast + 4 weight transposes ----------------
// blocks [0,8192): cast; [8192,8448): WQ; +256: WK; +256: WV; +256: Wout.
__global__ __launch_bounds__(256) void prep_fused(
    const float* __restrict__ resid, const float* __restrict__ WQ,
    const float* __restrict__ WK, const float* __restrict__ WV,
    const float* __restrict__ Wout,
    unsigned short* __restrict__ residb, unsigned short* __restrict__ Wqkvt,
    unsigned short* __restrict__ W2t)
{
    const int bid = blockIdx.x;
    if (bid < 8192) {                     // cast 8192*1024 floats, float4 per thread
        const int i = bid * 256 + threadIdx.x;
        const float4 v = ((const float4*)resid)[i];
        s16x4 o;
        o[0] = f2bf(v.x); o[1] = f2bf(v.y); o[2] = f2bf(v.z); o[3] = f2bf(v.w);
        *(s16x4*)(residb + (size_t)i * 4) = o;
        return;
    }
    __shared__ unsigned short tile[64][66];
    const int id2 = bid - 8192;
    const int which = id2 >> 8;           // 0..3
    const int sub = id2 & 255;
    const int tx = threadIdx.x & 63, ty = threadIdx.x >> 6;
    if (which < 3) {                      // W[k][n] 1024x1024 -> Wt[n][k] bf16
        const float* W = which == 0 ? WQ : (which == 1 ? WK : WV);
        unsigned short* Wt = Wqkvt + (size_t)which * 1024 * 1024;
        const int n0 = (sub & 15) * 64, k0 = (sub >> 4) * 64;
        #pragma unroll
        for (int i = ty; i < 64; i += 4)
            tile[i][tx] = (unsigned short)f2bf(W[(size_t)(k0 + i) * 1024 + n0 + tx]);
        __syncthreads();
        #pragma unroll
        for (int i = ty; i < 64; i += 4)
            Wt[(size_t)(n0 + i) * 1024 + k0 + tx] = tile[tx][i];
    } else {                              // W_out[c][h][d] -> W2t[d][h*64+c]
        const int d0 = (sub & 15) * 64, h = sub >> 4;
        #pragma unroll
        for (int c = ty; c < 64; c += 4)
            tile[c][tx] = (unsigned short)f2bf(Wout[(size_t)(c * 16 + h) * 1024 + d0 + tx]);
        __syncthreads();
        #pragma unroll
        for (int i = ty; i < 64; i += 4)
            W2t[(size_t)(d0 + i) * 1024 + h * 64 + tx] = tile[tx][i];
    }
}

// ---------------- 2)/4) deep GEMM: 128x256 tile, counted-vmcnt -------------
// C[M][N] = A[M][1024] * Bt[N][1024]^T.
// MODE 1: N=3072, outputs split Q/K/Vt (bf16).  MODE 0: N=1024, fp32 C + bias.
// 8 waves (2M x 4N), per-wave C = 64x64 = acc[4][4] frags.
// LDS (dynamic, 96 KiB): 2 buffers x {A_klo[128][32], A_khi, B_klo[256][32],
// B_khi} (64-B row pitch). XOR swizzle key (row>>1)&3 on 16B slots: applied
// on the DMA SOURCE address (LDS dest linear) and on ds_read offsets ->
// b128 reads at the hardware-minimum 8 bank-cycles (conflict-free).
// Load groups (3x gld16 = 24 KB): Glo(t)={A_klo,B_klo0,B_klo1},
// Ghi(t)={A_khi,B_khi0,B_khi1} -> buf[t&1].
// Issue order: prologue Glo(0),Ghi(0),Glo(1); in-loop Ghi(t+1) @ kk0(t),
// Glo(t+2) @ kk1(t)  [targets proven idle]. Prefetch distance = 3 phases.
// Ledger (steady): 9 outstanding at each W-point, oldest 3 = group being
// consumed -> vmcnt(6). Tail: W1(15)=vmcnt(3), W2(15)=vmcnt(0).
template <int MODE>
__global__ __launch_bounds__(512, 2) void gemm_deep(
    const unsigned short* __restrict__ A,
    const unsigned short* __restrict__ Bt,
    unsigned short* __restrict__ Qb, unsigned short* __restrict__ Kb,
    unsigned short* __restrict__ Vt,
    float* __restrict__ Cf, const float* __restrict__ bias)
{
    extern __shared__ __align__(16) unsigned short S[];
    constexpr int LDK = 1024, NT = 16;      // K=1024, BK=64
    constexpr int NBX = (MODE == 1) ? 12 : 4;   // N tiles of 256
    constexpr int XCH = (MODE == 1) ? 96 : 32;  // blocks per XCD (grid%8==0)
    const int tid = threadIdx.x, lane = tid & 63, w = tid >> 6;
    const int wm = w >> 2, wn = w & 3;      // 2 x 4 waves
    const int quad = lane >> 4, fl = lane & 15;

    const int wg  = blockIdx.x;
    const int swz = (wg & 7) * XCH + (wg >> 3);
    const int bx  = swz % NBX, by = swz / NBX;
    const int m0  = by * 128, n0 = bx * 256;

    // --- staging sources. One gld16 = 512 thr x 16 B = 8 KB (one A-half /
    // half a B-half). thread tid -> arena row tid/4, phys slot tid&3;
    // source k-chunk = (tid&3) ^ ((tid>>3)&3)  [key (row>>1)&3].
    const int srow = tid >> 2;                                  // 0..127
    const int sk   = ((tid & 3) ^ ((tid >> 3) & 3)) * 8;        // shorts
    const unsigned short* pa  = A  + (size_t)(m0 + srow) * LDK + sk;
    const unsigned short* pb0 = Bt + (size_t)(n0 + srow) * LDK + sk;
    const unsigned short* pb1 = Bt + (size_t)(n0 + 128 + srow) * LDK + sk;
    const int dst = tid * 8;                 // LDS shorts within arena

    // --- compute-side LDS read offsets (shorts). key = (fl>>1)&3 for all frags.
    const int sx   = (quad ^ ((fl >> 1) & 3)) * 8;
    const int arow = (wm * 64 + fl) * 32 + sx;           // A_klo@0, A_khi@4096
    const int brow = 8192 + (wn * 64 + fl) * 32 + sx;    // B_klo@8192, B_khi@16384

    f32x4 acc[4][4];
    #pragma unroll
    for (int m = 0; m < 4; ++m)
        #pragma unroll
        for (int n = 0; n < 4; ++n) acc[m][n] = (f32x4){0.f, 0.f, 0.f, 0.f};

    // --- prologue: Glo(0), Ghi(0) -> buf0; Glo(1) -> buf1. (9 loads) ---
    gld16(pa,       S + dst);                // A_klo(0)
    gld16(pb0,      S + 8192 + dst);         // B_klo(0) rows 0-127
    gld16(pb1,      S + 12288 + dst);        // B_klo(0) rows 128-255
    gld16(pa + 32,  S + 4096 + dst);         // A_khi(0)
    gld16(pb0 + 32, S + 16384 + dst);        // B_khi(0) rows 0-127
    gld16(pb1 + 32, S + 20480 + dst);        // B_khi(0) rows 128-255
    gld16(pa + 64,  S + 24576 + dst);        // A_klo(1)
    gld16(pb0 + 64, S + 24576 + 8192 + dst); // B_klo(1) rows 0-127
    gld16(pb1 + 64, S + 24576 + 12288 + dst);// B_klo(1) rows 128-255

    for (int t = 0; t < NT; ++t) {
        unsigned short* Sc = S + (t & 1) * 24576;
        unsigned short* Sn = S + ((t & 1) ^ 1) * 24576;

        // W1: Glo(t) landed (oldest 3 of 9 in steady state).
        if (t < NT - 1) asm volatile("s_waitcnt vmcnt(6)" ::: "memory");
        else            asm volatile("s_waitcnt vmcnt(3)" ::: "memory");
        __builtin_amdgcn_s_barrier();

        s16x8 af[4], bfr[4];
        // ---- phase kk=0: read klo(t), issue Ghi(t+1) -> Sn.khi ----
        #pragma unroll
        for (int mi = 0; mi < 4; ++mi) af[mi]  = *(const s16x8*)(Sc + arow + mi * 512);
        #pragma unroll
        for (int ni = 0; ni < 4; ++ni) bfr[ni] = *(const s16x8*)(Sc + brow + ni * 512);
        if (t < NT - 1) {
            const int ka = (t + 1) * 64 + 32;
            gld16(pa + ka,  Sn + 4096 + dst);            // A_khi(t+1)
            gld16(pb0 + ka, Sn + 16384 + dst);           // B_khi(t+1)
            gld16(pb1 + ka, Sn + 20480 + dst);
        }
        asm volatile("" ::: "memory");
        __builtin_amdgcn_s_barrier();
        __builtin_amdgcn_s_setprio(1);
        #pragma unroll
        for (int mi = 0; mi < 4; ++mi)
            #pragma unroll
            for (int ni = 0; ni < 4; ++ni)
                acc[mi][ni] = MFMA_BF16(af[mi], bfr[ni], acc[mi][ni]);
        __builtin_amdgcn_s_setprio(0);

        // W2: Ghi(t) landed.
        if (t < NT - 1) asm volatile("s_waitcnt vmcnt(6)" ::: "memory");
        else            asm volatile("s_waitcnt vmcnt(0)" ::: "memory");
        __builtin_amdgcn_s_barrier();
        // ---- phase kk=1: read khi(t), issue Glo(t+2) -> Sc.klo ----
        // (Sc.klo's reads all completed before the W2 barrier above.)
        #pragma unroll
        for (int mi = 0; mi < 4; ++mi) af[mi]  = *(const s16x8*)(Sc + 4096 + arow + mi * 512);
        #pragma unroll
        for (int ni = 0; ni < 4; ++ni) bfr[ni] = *(const s16x8*)(Sc + 8192 + brow + ni * 512);
        if (t < NT - 2) {
            const int ka = (t + 2) * 64;
            gld16(pa + ka,  Sc + dst);                   // A_klo(t+2)
            gld16(pb0 + ka, Sc + 8192 + dst);            // B_klo(t+2)
            gld16(pb1 + ka, Sc + 12288 + dst);
        }
        asm volatile("" ::: "memory");
        __builtin_amdgcn_s_barrier();
        __builtin_amdgcn_s_setprio(1);
        #pragma unroll
        for (int mi = 0; mi < 4; ++mi)
            #pragma unroll
            for (int ni = 0; ni < 4; ++ni)
                acc[mi][ni] = MFMA_BF16(af[mi], bfr[ni], acc[mi][ni]);
        __builtin_amdgcn_s_setprio(0);
        // loop top of t+1 = W1 wait + barrier (keeps ds reads of buf safe).
    }

    // ---- epilogue. C/D frag layout: row = quad*4 + r, col = fl. ----
    if (MODE == 0) {
        #pragma unroll
        for (int ni = 0; ni < 4; ++ni) {
            const int col = n0 + wn * 64 + ni * 16 + fl;
            const float bv = bias[col];
            #pragma unroll
            for (int mi = 0; mi < 4; ++mi) {
                const int row = m0 + wm * 64 + mi * 16 + quad * 4;
                #pragma unroll
                for (int r = 0; r < 4; ++r)
                    Cf[(size_t)(row + r) * 1024 + col] = acc[mi][ni][r] + bv;
            }
        }
    } else {
        // Block cols span exactly one of Q/K/V (n0 multiple of 256).
        const int which = n0 >> 10;
        if (which < 2) {
            unsigned short* O = which == 0 ? Qb : Kb;
            const int cbase = (n0 & 1023) + wn * 64;
            #pragma unroll
            for (int mi = 0; mi < 4; ++mi) {
                const int row = m0 + wm * 64 + mi * 16 + quad * 4;
                #pragma unroll
                for (int ni = 0; ni < 4; ++ni) {
                    const int col = cbase + ni * 16 + fl;
                    #pragma unroll
                    for (int r = 0; r < 4; ++r)
                        O[(size_t)(row + r) * 1024 + col] = (unsigned short)f2bf(acc[mi][ni][r]);
                }
            }
        } else {
            // V transposed: Vt[((b*16+h)*64+c)][s]; r-values s-consecutive -> 8B store
            const int hh = ((n0 - 2048) >> 6) + wn;             // wave-uniform head
            #pragma unroll
            for (int mi = 0; mi < 4; ++mi) {
                const int token = m0 + wm * 64 + mi * 16 + quad * 4;
                const int bb = token >> 11, ss = token & 2047;
                #pragma unroll
                for (int ni = 0; ni < 4; ++ni) {
                    const int cl = ni * 16 + fl;
                    s16x4 pv;
                    pv[0] = f2bf(acc[mi][ni][0]); pv[1] = f2bf(acc[mi][ni][1]);
                    pv[2] = f2bf(acc[mi][ni][2]); pv[3] = f2bf(acc[mi][ni][3]);
                    *(s16x4*)(Vt + (size_t)((bb * 16 + hh) * 64 + cl) * 2048 + ss) = pv;
                }
            }
        }
    }
}

// ---------------- 3) attention tile body (DIAG templated) ----------------
// ls accumulation on the matrix pipe: lsa[g] += ones^T . P (rowsum of the
// bf16 P actually used in PV -> denominator matches numerator). All D rows
// equal -> final ls = lsa[g][0], no cross-lane reduce.
template <bool DIAG>
__device__ __forceinline__ void attn_tile(
    int s0, int wl, int wq0, int fl, int quad,
    const unsigned short* __restrict__ KV, const unsigned short* __restrict__ Vs,
    unsigned short* __restrict__ PbW,
    const s16x8 (&qfr)[2][2], f32x4 (&zt)[2][4], f32x4 (&lsa)[2])
{
    const float SC = 0.18033688011112042f;   // (1/sqrt(64)) * log2(e)
    const float M  = 32.0f;                  // fixed softmax shift
    const s16x8 ones = {16256, 16256, 16256, 16256, 16256, 16256, 16256, 16256};
    #pragma unroll
    for (int c4 = 0; c4 < 4; ++c4) {
        if (DIAG && c4 > wl) break;          // wave-uniform causal skip
        #pragma unroll
        for (int e = 0; e < 2; ++e) {
            const int f = 2 * c4 + e;
            const unsigned short* Krow = KV + (f * 16 + fl) * 72;
            const s16x8 kf0 = *(const s16x8*)(Krow + quad * 8);
            const s16x8 kf1 = *(const s16x8*)(Krow + 32 + quad * 8);
            #pragma unroll
            for (int g = 0; g < 2; ++g) {
                unsigned short* pw = PbW + (g * 16 + fl) * 36 + e * 16 + quad * 4;
                if (DIAG && f > 2 * wl + g) { // fully masked frag: zero-fill
                    *(s16x4*)pw = (s16x4){0, 0, 0, 0};
                } else {
                    f32x4 z = (f32x4){0.f, 0.f, 0.f, 0.f};
                    z = MFMA_BF16(kf0, qfr[g][0], z);
                    z = MFMA_BF16(kf1, qfr[g][1], z);
                    float p[4];
                    #pragma unroll
                    for (int r = 0; r < 4; ++r) {
                        float arg = fmaf(z[r], SC, -M);
                        if (DIAG && f == 2 * wl + g) {   // diagonal frag only
                            const int s = s0 + f * 16 + quad * 4 + r;
                            const int qi = wq0 + g * 16 + fl;
                            if (s > qi) arg = -100.f;    // exp2 -> ~0
                        }
                        p[r] = EXP2(arg);
                    }
                    s16x4 pk;
                    pk[0] = f2bf(p[0]); pk[1] = f2bf(p[1]);
                    pk[2] = f2bf(p[2]); pk[3] = f2bf(p[3]);
                    *(s16x4*)pw = pk;
                }
            }
        }
        // PV + denominator for this 32-s chunk (MFMA cluster: setprio)
        const s16x8 pf0 = *(const s16x8*)(PbW + fl * 36 + quad * 8);
        const s16x8 pf1 = *(const s16x8*)(PbW + (16 + fl) * 36 + quad * 8);
        __builtin_amdgcn_s_setprio(1);
        lsa[0] = MFMA_BF16(ones, pf0, lsa[0]);
        lsa[1] = MFMA_BF16(ones, pf1, lsa[1]);
        #pragma unroll
        for (int mf = 0; mf < 4; ++mf) {
            const s16x8 vf = *(const s16x8*)(Vs + (mf * 16 + fl) * 136 + c4 * 32 + quad * 8);
            zt[0][mf] = MFMA_BF16(vf, pf0, zt[0][mf]);
            zt[1][mf] = MFMA_BF16(vf, pf1, zt[1][mf]);
        }
        __builtin_amdgcn_s_setprio(0);
    }
}

// ---------------- 3) causal flash attention, double-buffered gld16 ----------
// 256-thread blocks (4 waves), 128 q/block, grid 1024 heavy-first:
// qb = 15 - (lid>>6) (LPT). bh = lid&63 -> XCD = lid%8 = bh%8 keeps each
// XCD's 8 heads' K+V hot in its L2.
// K/V double buffer: at tile t, after the barrier, issue tile t+1's 35 gld16
// into buf^1 and compute from buf. The barrier's vmcnt(0) drain waits on
// loads issued one full tile's compute earlier (~2000+ cyc in flight) ->
// effectively free. One barrier per tile. DMA overwrite of buf^1 is safe:
// its last readers finished tile t-1 before this barrier. 79 KiB LDS ->
// 2 blocks/CU.
__global__ __launch_bounds__(256, 2) void attn_causal(
    const unsigned short* __restrict__ Qb,
    const unsigned short* __restrict__ Kb,
    const unsigned short* __restrict__ Vt,
    unsigned short* __restrict__ Zb)
{
    __shared__ __align__(16) unsigned short KV2[2][17920];  // K: 128x72 sh, V: 64x136 sh
    __shared__ __align__(16) unsigned short Pb[4][32 * 36]; // per wave [32 q][32 s + pad]
    const int tid = threadIdx.x, lane = tid & 63, w = tid >> 6;
    const int quad = lane >> 4, fl = lane & 15;
    const int lid = blockIdx.x;
    const int qb = 15 - (lid >> 6);             // heavy-first
    const int bh = lid & 63, b = bh >> 4, h = bh & 15;
    const int wq0 = qb * 128 + w * 32;          // wave's first q row
    const int wl = w;                           // wave's slot in the 128-q tile

    const unsigned short* Kbase = Kb + (size_t)b * 2048 * 1024 + h * 64;
    const unsigned short* Vbase = Vt + (size_t)bh * 64 * 2048;
    unsigned short* PbW = Pb[w];

    // Q fragments: [g][half]
    s16x8 qfr[2][2];
    #pragma unroll
    for (int g = 0; g < 2; ++g) {
        const unsigned short* Qrow = Qb + (size_t)(b * 2048 + wq0 + g * 16 + fl) * 1024 + h * 64;
        qfr[g][0] = *(const s16x8*)(Qrow + quad * 8);
        qfr[g][1] = *(const s16x8*)(Qrow + 32 + quad * 8);
    }

    // Staging map: 35 chunks over 4 waves (waves 0-2 get 9, wave 3 gets 8).
    const unsigned short* gsp[9];
    int sadv[9];
    unsigned ldsb[9];
    #pragma unroll
    for (int i = 0; i < 9; ++i) {
        const int W = w + 4 * i;
        if (W < 35) {
            const int c = W * 64 + lane;
            if (c < 1152) {
                const int r = c / 9, cl0 = c % 9;
                const int cl = (cl0 == 8) ? 0 : cl0;
                gsp[i] = Kbase + r * 1024 + cl * 8;  sadv[i] = 128 * 1024;
            } else {
                const int cc = c - 1152;
                const int r = cc / 17, cl0 = cc % 17;
                const int cl = (cl0 == 16) ? 0 : cl0;
                gsp[i] = Vbase + r * 2048 + cl * 8;  sadv[i] = 128;
            }
            ldsb[i] = (unsigned)c * 8u;
        }
    }

    f32x4 zt[2][4];                              // [g][mf] accumulators
    #pragma unroll
    for (int g = 0; g < 2; ++g)
        #pragma unroll
        for (int mf = 0; mf < 4; ++mf) zt[g][mf] = (f32x4){0.f, 0.f, 0.f, 0.f};
    f32x4 lsa[2] = {(f32x4){0.f, 0.f, 0.f, 0.f}, (f32x4){0.f, 0.f, 0.f, 0.f}};
    const int ntiles = qb + 1;

    // prologue: stage tile 0 into buf 0.
    #pragma unroll
    for (int i = 0; i < 9; ++i)
        if (w + 4 * i < 35) {
            gld16(gsp[i], KV2[0] + ldsb[i]);
            gsp[i] += sadv[i];
        }

    for (int kt = 0; kt < ntiles; ++kt) {
        const int cb = kt & 1;
        // Drain own outstanding DMAs (tile kt's, issued a full tile ago),
        // then barrier -> every wave's chunks for tile kt are visible.
        asm volatile("s_waitcnt vmcnt(0)" ::: "memory");
        __syncthreads();
        // Prefetch tile kt+1 into the other buffer (its last readers
        // finished at tile kt-1, before the barrier above).
        if (kt + 1 < ntiles) {
            #pragma unroll
            for (int i = 0; i < 9; ++i)
                if (w + 4 * i < 35) {
                    gld16(gsp[i], KV2[cb ^ 1] + ldsb[i]);
                    gsp[i] += sadv[i];
                }
        }
        if (kt < qb) {
            attn_tile<false>(kt << 7, wl, wq0, fl, quad, KV2[cb], KV2[cb] + 9216,
                             PbW, qfr, zt, lsa);
        } else {
            attn_tile<true>(kt << 7, wl, wq0, fl, quad, KV2[cb], KV2[cb] + 9216,
                            PbW, qfr, zt, lsa);
        }
    }
    // ---- normalize + store Z. lsa rows all equal -> element 0 is the rowsum.
    #pragma unroll
    for (int g = 0; g < 2; ++g) {
        const float inv = RCP(lsa[g][0]);
        unsigned short* Zrow = Zb + (size_t)(b * 2048 + wq0 + g * 16 + fl) * 1024 + h * 64;
        #pragma unroll
        for (int mf = 0; mf < 4; ++mf) {
            s16x4 o;
            o[0] = f2bf(zt[g][mf][0] * inv); o[1] = f2bf(zt[g][mf][1] * inv);
            o[2] = f2bf(zt[g][mf][2] * inv); o[3] = f2bf(zt[g][mf][3] * inv);
            *(s16x4*)(Zrow + mf * 16 + quad * 4) = o;
        }
    }
}

// ---------------- launch ----------------
extern "C" void kernel_launch(void* const* d_in, const int* in_sizes, int n_in,
                              void* d_out, int out_size, void* d_ws, size_t ws_size,
                              hipStream_t stream) {
    const float* resid = (const float*)d_in[0];
    const float* WQ    = (const float*)d_in[1];
    const float* WK    = (const float*)d_in[2];
    const float* WV    = (const float*)d_in[3];
    const float* Wout  = (const float*)d_in[4];
    const float* bout  = (const float*)d_in[5];
    float* out = (float*)d_out;

    char* p = (char*)d_ws;
    auto alloc = [&](size_t bytes) { void* r = (void*)p; p += (bytes + 255) & ~(size_t)255; return r; };
    unsigned short* residb = (unsigned short*)alloc(8192ull * 1024 * 2);
    unsigned short* Wqkvt  = (unsigned short*)alloc(3072ull * 1024 * 2);
    unsigned short* W2t    = (unsigned short*)alloc(1024ull * 1024 * 2);
    unsigned short* Qbuf   = (unsigned short*)alloc(8192ull * 1024 * 2);
    unsigned short* Kbuf   = (unsigned short*)alloc(8192ull * 1024 * 2);
    unsigned short* Vtb    = (unsigned short*)alloc(64ull * 64 * 2048 * 2);
    unsigned short* Zbuf   = (unsigned short*)alloc(8192ull * 1024 * 2);

    static bool s_attr = false;
    if (!s_attr) {                           // host-side attr set; graph-capture-safe
        hipFuncSetAttribute(reinterpret_cast<const void*>(gemm_deep<1>),
                            hipFuncAttributeMaxDynamicSharedMemorySize, 98304);
        hipFuncSetAttribute(reinterpret_cast<const void*>(gemm_deep<0>),
                            hipFuncAttributeMaxDynamicSharedMemorySize, 98304);
        s_attr = true;
    }

    prep_fused<<<9216, 256, 0, stream>>>(resid, WQ, WK, WV, Wout, residb, Wqkvt, W2t);
    gemm_deep<1><<<768, 512, 98304, stream>>>(residb, Wqkvt, Qbuf, Kbuf, Vtb,
                                              nullptr, nullptr);
    attn_causal<<<1024, 256, 0, stream>>>(Qbuf, Kbuf, Vtb, Zbuf);
    gemm_deep<0><<<256, 512, 98304, stream>>>(Zbuf, W2t, nullptr, nullptr, nullptr,
                                              out, bout);
}